// Round 12
// baseline (191.653 us; speedup 1.0000x reference)
//
#include <hip/hip_runtime.h>
#include <hip/hip_bf16.h>

typedef unsigned short u16;
typedef unsigned int   u32;

typedef __bf16 bf16x8 __attribute__((ext_vector_type(8)));
typedef float  f32x4  __attribute__((ext_vector_type(4)));

__device__ __forceinline__ u16 f2b(float f) {
    __hip_bfloat16 h = __float2bfloat16(f);
    u16 u; __builtin_memcpy(&u, &h, 2); return u;
}
__device__ __forceinline__ float blo(u32 u) { return __uint_as_float(u << 16); }
__device__ __forceinline__ float bhi(u32 u) { return __uint_as_float(u & 0xffff0000u); }

// ---------------------------------------------------------------------------
// prep (input padding ELIMINATED — conv stages fp32 directly):
//  section B (blocks [0,1152)):    weights -> MFMA B-fragment order
//       BF[(((p*4+kk)*4+q)*256 + n)*8 + j] = bf16(w[(p*128+kk*32+q*8+j)*256+n])
//  section C (blocks [1152,1200)): zero s0,s2,s3 (12288 floats)
// ---------------------------------------------------------------------------
__global__ void k_prep(const float* __restrict__ wk,
                       u16* __restrict__ BF, float* __restrict__ stats) {
    int bx = blockIdx.x, tid = threadIdx.x;
    if (bx < 1152) {
        int t = bx * 256 + tid;                   // 294912 total, exact
        int j  = t & 7;
        int n  = (t >> 3) & 255;
        int q  = (t >> 11) & 3;
        int kk = (t >> 13) & 3;
        int p  = t >> 15;
        BF[t] = f2b(wk[(p * 128 + kk * 32 + q * 8 + j) * 256 + n]);
    } else {
        stats[(bx - 1152) * 256 + tid] = 0.f;     // 12288 floats
    }
}

// ---------------------------------------------------------------------------
// conv: implicit GEMM (R4 ping-pong — measured plateau, no spill).
// Block = one image row: M=64, N=256, K=1152. 4 waves, wave tile 64x64
// (4x4 16x16x32 bf16 MFMA). A staged per channel-half DIRECTLY from the
// fp32 input: predicated dwordx4 loads + cvt + ds_write_b128 (borders ->
// zeros in-kernel; the 17.8MB pad tensor and 78% of prep are gone).
// Same swizzled LDS layout [pr][wp][cs^(wp&7)]. B fragments from L2 in
// fragment order, register ping-pong, barrier-free K-loop.
// Epilogue: +bias, relu, store x bf16, atomically accumulate s0 = sum_n x.
// ---------------------------------------------------------------------------
__launch_bounds__(256, 2)
__global__ void k_conv(const float* __restrict__ in, const u16* __restrict__ BF,
                       const float* __restrict__ bias,
                       u16* __restrict__ X, float* __restrict__ s0) {
    __shared__ u16 ldsA[12672];                   // 3*66*8 chunks = 25344 B
    const int t = threadIdx.x;
    const int lane = t & 63, wid = t >> 6;        // 4 waves
    const int q = lane >> 4, l15 = lane & 15;
    const int bb = blockIdx.x >> 6;               // batch
    const int h  = blockIdx.x & 63;               // output row
    const int wn0 = wid << 6;                     // wave's n-offset (64 each)

    // stage channel-half S from fp32 input; LDS[pr][wp][cs] = in[.., cs^(wp&7)]
#define STAGE(S) { \
    const int sb0 = wid * 396; \
    _Pragma("unroll") for (int i = 0; i < 7; ++i) { \
        int slot = sb0 + i * 64 + lane; \
        if (i < 6 || lane < 12) { \
            int pr = slot / 528; int rem = slot - pr * 528; \
            int wp = rem >> 3, cs = rem & 7; \
            int gc = (S) * 8 + (cs ^ (wp & 7)); \
            int y = h + pr - 1, x = wp - 1; \
            u16 ov[8]; \
            if (y >= 0 && y < 64 && x >= 0 && x < 64) { \
                const float4* s4 = (const float4*)(in + \
                    (((bb * 64 + y) * 64 + x) * 128 + gc * 8)); \
                float4 f0 = s4[0], f1 = s4[1]; \
                ov[0]=f2b(f0.x); ov[1]=f2b(f0.y); ov[2]=f2b(f0.z); ov[3]=f2b(f0.w); \
                ov[4]=f2b(f1.x); ov[5]=f2b(f1.y); ov[6]=f2b(f1.z); ov[7]=f2b(f1.w); \
            } else { \
                _Pragma("unroll") for (int j = 0; j < 8; ++j) ov[j] = 0; \
            } \
            uint4 wv; __builtin_memcpy(&wv, ov, 16); \
            *(uint4*)((char*)ldsA + slot * 16) = wv; \
        } \
    } }

#define LOADB(B, P, S) { \
    _Pragma("unroll") for (int kk = 0; kk < 2; ++kk) \
    _Pragma("unroll") for (int ni = 0; ni < 4; ++ni) \
        B[kk * 4 + ni] = *(const bf16x8*)(BFl + (P) * 32768 + \
                                          ((S) * 2 + kk) * 8192 + ni * 128); }

#define COMPP(B, DH, DW) { \
    _Pragma("unroll") for (int kk = 0; kk < 2; ++kk) { \
        bf16x8 af[4]; \
        _Pragma("unroll") for (int mi = 0; mi < 4; ++mi) { \
            int wp = mi * 16 + l15 + (DW); \
            int swz = (kk * 4 + q) ^ (wp & 7); \
            af[mi] = *(const bf16x8*)((const char*)ldsA + \
                (((DH) * 528 + wp * 8 + swz) << 4)); \
        } \
        _Pragma("unroll") for (int mi = 0; mi < 4; ++mi) \
        _Pragma("unroll") for (int ni = 0; ni < 4; ++ni) \
            acc[mi][ni] = __builtin_amdgcn_mfma_f32_16x16x32_bf16( \
                af[mi], B[kk * 4 + ni], acc[mi][ni], 0, 0, 0); } }

    const u16* BFl = BF + (q * 2048 + (wn0 + l15) * 8);

    f32x4 zero = {0.f, 0.f, 0.f, 0.f};
    f32x4 acc[4][4];
    #pragma unroll
    for (int mi = 0; mi < 4; ++mi)
        #pragma unroll
        for (int ni = 0; ni < 4; ++ni) acc[mi][ni] = zero;

    bf16x8 B0[8], B1[8];

    // ---- channel half 0 ----
    STAGE(0);
    __syncthreads();
    LOADB(B0, 0, 0);
    LOADB(B1, 1, 0); COMPP(B0, 0, 0);
    LOADB(B0, 2, 0); COMPP(B1, 0, 1);
    LOADB(B1, 3, 0); COMPP(B0, 0, 2);
    LOADB(B0, 4, 0); COMPP(B1, 1, 0);
    LOADB(B1, 5, 0); COMPP(B0, 1, 1);
    LOADB(B0, 6, 0); COMPP(B1, 1, 2);
    LOADB(B1, 7, 0); COMPP(B0, 2, 0);
    LOADB(B0, 8, 0); COMPP(B1, 2, 1);
    COMPP(B0, 2, 2);
    __syncthreads();                              // all half-0 LDS reads done

    // ---- channel half 1 ----
    STAGE(1);
    __syncthreads();
    LOADB(B0, 0, 1);
    LOADB(B1, 1, 1); COMPP(B0, 0, 0);
    LOADB(B0, 2, 1); COMPP(B1, 0, 1);
    LOADB(B1, 3, 1); COMPP(B0, 0, 2);
    LOADB(B0, 4, 1); COMPP(B1, 1, 0);
    LOADB(B1, 5, 1); COMPP(B0, 1, 1);
    LOADB(B0, 6, 1); COMPP(B1, 1, 2);
    LOADB(B1, 7, 1); COMPP(B0, 2, 0);
    LOADB(B0, 8, 1); COMPP(B1, 2, 1);
    COMPP(B0, 2, 2);

    // epilogue: bias + relu, store bf16 x, column sums -> s0
    float bv[4];
    #pragma unroll
    for (int ni = 0; ni < 4; ++ni) bv[ni] = bias[wn0 + ni * 16 + l15];
    float colsum[4] = {0.f, 0.f, 0.f, 0.f};
    u16* xrow = X + (((bb << 12) + (h << 6) + q * 4) * 256) + wn0 + l15;
    #pragma unroll
    for (int mi = 0; mi < 4; ++mi) {
        #pragma unroll
        for (int rr = 0; rr < 4; ++rr) {
            u16* xp = xrow + (mi * 16 + rr) * 256;
            #pragma unroll
            for (int ni = 0; ni < 4; ++ni) {
                float v = acc[mi][ni][rr] + bv[ni];
                v = v > 0.f ? v : 0.f;
                xp[ni * 16] = f2b(v);
                colsum[ni] += v;
            }
        }
    }
    #pragma unroll
    for (int ni = 0; ni < 4; ++ni) {
        float c = colsum[ni];
        c += __shfl_xor(c, 16);
        c += __shfl_xor(c, 32);
        if (lane < 16) atomicAdd(&s0[bb * 256 + wn0 + ni * 16 + l15], c);
    }
#undef STAGE
#undef LOADB
#undef COMPP
}

// ---------------------------------------------------------------------------
// routing pass v4: 256 blocks x 256 positions (4x work/block vs v3 — amortize
// launch/ramp). vsum = l2n(Sa) (+ l2n(Sb)) register-cached -> ONE dot per
// position. Stride-17 LDS, rotating depth-4 X prefetch, shfl n-reduce.
// thread (c=t&15, nl=t>>4). b-logits bounded -> no softmax max pass.
// ---------------------------------------------------------------------------
__launch_bounds__(256, 4)
__global__ void k_pass(const u16* __restrict__ X, const float* __restrict__ Sa,
                       const float* __restrict__ Sb, float* __restrict__ Sout,
                       int use2) {
    __shared__ float vs[272];                     // [cap*17 + d]
    __shared__ float red[4 * 272];                // [wave][c*17 + d]
    const int t = threadIdx.x, b = blockIdx.y, chunk = blockIdx.x;
    const int c = t & 15, nl = t >> 4;
    const int lane = t & 63, wid = t >> 6;
    const u16* xbase = X + ((b << 12) + chunk * 256 + nl) * 256 + c * 16;

    // prefetch first 4 rounds (8 outstanding 16B loads) before the v-compute
    uint4 pa[4][2];
    #pragma unroll
    for (int r0 = 0; r0 < 4; ++r0) {
        pa[r0][0] = ((const uint4*)(xbase + r0 * 4096))[0];
        pa[r0][1] = ((const uint4*)(xbase + r0 * 4096))[1];
    }
    {
        float sa = Sa[b * 256 + t];
        float ss = sa * sa;
        #pragma unroll
        for (int off = 1; off < 16; off <<= 1) ss += __shfl_xor(ss, off);
        ss = ss < 1e-12f ? 1e-12f : ss;
        float vv = sa / sqrtf(ss);
        if (use2) {
            float sb = Sb[b * 256 + t];
            float s2v = sb * sb;
            #pragma unroll
            for (int off = 1; off < 16; off <<= 1) s2v += __shfl_xor(s2v, off);
            s2v = s2v < 1e-12f ? 1e-12f : s2v;
            vv += sb / sqrtf(s2v);
        }
        vs[(t >> 4) * 17 + (t & 15)] = vv;
    }
    __syncthreads();
    float vr[16];
    #pragma unroll
    for (int d = 0; d < 16; ++d) vr[d] = vs[c * 17 + d];

    float acc[16];
    #pragma unroll
    for (int d = 0; d < 16; ++d) acc[d] = 0.f;

    #pragma unroll
    for (int r = 0; r < 16; ++r) {
        uint4 a0 = pa[r & 3][0], a1 = pa[r & 3][1];
        if (r < 12) {
            pa[r & 3][0] = ((const uint4*)(xbase + (r + 4) * 4096))[0];
            pa[r & 3][1] = ((const uint4*)(xbase + (r + 4) * 4096))[1];
        }
        u32 us[8] = {a0.x, a0.y, a0.z, a0.w, a1.x, a1.y, a1.z, a1.w};
        float xf[16];
        #pragma unroll
        for (int j = 0; j < 8; ++j) { xf[2*j] = blo(us[j]); xf[2*j+1] = bhi(us[j]); }
        float bvv = 0.f;
        #pragma unroll
        for (int d = 0; d < 16; ++d) bvv += xf[d] * vr[d];
        float e = __expf(bvv);                    // |b| small: stable w/o max
        float sm = e;
        #pragma unroll
        for (int off = 1; off < 16; off <<= 1) sm += __shfl_xor(sm, off);
        float w = e / sm;
        #pragma unroll
        for (int d = 0; d < 16; ++d) acc[d] += w * xf[d];
    }
    // reduce the wave's 4 nl groups (lanes +-16, +-32) -> lanes 0..15
    #pragma unroll
    for (int d = 0; d < 16; ++d) {
        acc[d] += __shfl_xor(acc[d], 16);
        acc[d] += __shfl_xor(acc[d], 32);
    }
    if (lane < 16) {
        #pragma unroll
        for (int d = 0; d < 16; ++d) red[wid * 272 + lane * 17 + d] = acc[d];
    }
    __syncthreads();
    {
        int c2 = t >> 4, d2 = t & 15;
        float tot = red[c2 * 17 + d2]       + red[272 + c2 * 17 + d2]
                  + red[544 + c2 * 17 + d2] + red[816 + c2 * 17 + d2];
        atomicAdd(&Sout[b * 256 + t], tot);
    }
}

// ---------------------------------------------------------------------------
// final: v = l2_normalize(s3), broadcast to (B,64,64,256) fp32.
// v hoisted to a register (loop-invariant per thread).
// ---------------------------------------------------------------------------
__launch_bounds__(256, 4)
__global__ void k_bcast(const float* __restrict__ S, float* __restrict__ Out) {
    __shared__ float vls[256];
    int t = threadIdx.x, bx = blockIdx.x, b = blockIdx.y;
    float s = S[b * 256 + t];
    float ss = s * s;
    #pragma unroll
    for (int off = 1; off < 16; off <<= 1) ss += __shfl_xor(ss, off);
    ss = ss < 1e-12f ? 1e-12f : ss;
    vls[t] = s / sqrtf(ss);
    __syncthreads();
    float4 myv = ((const float4*)vls)[t & 63];    // (j*256+t)&63 == t&63
    float4* o = (float4*)Out + (long)b * 262144 + bx * 4096;
    #pragma unroll
    for (int j = 0; j < 16; ++j) o[j * 256 + t] = myv;
}

// ---------------------------------------------------------------------------
extern "C" void kernel_launch(void* const* d_in, const int* in_sizes, int n_in,
                              void* d_out, int out_size, void* d_ws, size_t ws_size,
                              hipStream_t stream) {
    const float* in   = (const float*)d_in[0];   // (16,64,64,128)
    const float* wk   = (const float*)d_in[1];   // (3,3,128,256)
    const float* bias = (const float*)d_in[2];   // (256,)
    float* out = (float*)d_out;
    char* ws = (char*)d_ws;

    // workspace layout (bytes) — pad tensor eliminated
    const size_t OFF_BF  = 0;                    // 294912*2      =    589,824
    const size_t OFF_X   = 589824;               // 16*4096*256*2 = 33,554,432
    const size_t OFF_ST  = 34144256;             // s0,s2,s3      = 3*16,384
    const size_t NEEDED  = OFF_ST + 3 * 16384;
    if (ws_size < NEEDED) return;                // fail loudly (validation error)

    u16* BF  = (u16*)(ws + OFF_BF);
    u16* X   = (u16*)(ws + OFF_X);
    float* s0 = (float*)(ws + OFF_ST);
    float* s2 = s0 + 4096;
    float* s3 = s2 + 4096;

    k_prep <<<1200, 256, 0, stream>>>(wk, BF, s0);
    k_conv <<<1024, 256, 0, stream>>>(in, BF, bias, X, s0);
    k_pass <<<dim3(16, 16), 256, 0, stream>>>(X, s0, s0, s2, 0);
    k_pass <<<dim3(16, 16), 256, 0, stream>>>(X, s0, s2, s3, 1);
    k_bcast<<<dim3(64, 16), 256, 0, stream>>>(s3, out);
}

// Round 13
// 159.914 us; speedup vs baseline: 1.1985x; 1.1985x over previous
//
#include <hip/hip_runtime.h>
#include <hip/hip_bf16.h>

typedef unsigned short u16;
typedef unsigned int   u32;

typedef __bf16 bf16x8 __attribute__((ext_vector_type(8)));
typedef float  f32x4  __attribute__((ext_vector_type(4)));

__device__ __forceinline__ u16 f2b(float f) {
    __hip_bfloat16 h = __float2bfloat16(f);
    u16 u; __builtin_memcpy(&u, &h, 2); return u;
}
__device__ __forceinline__ float blo(u32 u) { return __uint_as_float(u << 16); }
__device__ __forceinline__ float bhi(u32 u) { return __uint_as_float(u & 0xffff0000u); }

// ---------------------------------------------------------------------------
// prep (input padding eliminated — conv stages fp32 directly):
//  section B (blocks [0,1152)):    weights -> MFMA B-fragment order
//       BF[(((p*4+kk)*4+q)*256 + n)*8 + j] = bf16(w[(p*128+kk*32+q*8+j)*256+n])
//  section C (blocks [1152,1200)): zero s0,s2,s3 (12288 floats)
// ---------------------------------------------------------------------------
__global__ void k_prep(const float* __restrict__ wk,
                       u16* __restrict__ BF, float* __restrict__ stats) {
    int bx = blockIdx.x, tid = threadIdx.x;
    if (bx < 1152) {
        int t = bx * 256 + tid;                   // 294912 total, exact
        int j  = t & 7;
        int n  = (t >> 3) & 255;
        int q  = (t >> 11) & 3;
        int kk = (t >> 13) & 3;
        int p  = t >> 15;
        BF[t] = f2b(wk[(p * 128 + kk * 32 + q * 8 + j) * 256 + n]);
    } else {
        stats[(bx - 1152) * 256 + tid] = 0.f;     // 12288 floats
    }
}

// ---------------------------------------------------------------------------
// conv: implicit GEMM (R4 ping-pong structure + R12 direct-A staging).
// Block = one image row: M=64, N=256, K=1152. 4 waves, wave tile 64x64
// (4x4 16x16x32 bf16 MFMA). A staged per channel-half DIRECTLY from the
// fp32 input: predicated dwordx4 loads + cvt + ds_write_b128 (borders ->
// zeros in-kernel). Swizzled LDS layout [pr][wp][cs^(wp&7)]. B fragments
// from L2 in fragment order, register ping-pong, barrier-free K-loop.
// Epilogue: +bias, relu, store x bf16, atomically accumulate s0 = sum_n x.
// ---------------------------------------------------------------------------
__launch_bounds__(256, 2)
__global__ void k_conv(const float* __restrict__ in, const u16* __restrict__ BF,
                       const float* __restrict__ bias,
                       u16* __restrict__ X, float* __restrict__ s0) {
    __shared__ u16 ldsA[12672];                   // 3*66*8 chunks = 25344 B
    const int t = threadIdx.x;
    const int lane = t & 63, wid = t >> 6;        // 4 waves
    const int q = lane >> 4, l15 = lane & 15;
    const int bb = blockIdx.x >> 6;               // batch
    const int h  = blockIdx.x & 63;               // output row
    const int wn0 = wid << 6;                     // wave's n-offset (64 each)

    // stage channel-half S from fp32 input; LDS[pr][wp][cs] = in[.., cs^(wp&7)]
#define STAGE(S) { \
    const int sb0 = wid * 396; \
    _Pragma("unroll") for (int i = 0; i < 7; ++i) { \
        int slot = sb0 + i * 64 + lane; \
        if (i < 6 || lane < 12) { \
            int pr = slot / 528; int rem = slot - pr * 528; \
            int wp = rem >> 3, cs = rem & 7; \
            int gc = (S) * 8 + (cs ^ (wp & 7)); \
            int y = h + pr - 1, x = wp - 1; \
            u16 ov[8]; \
            if (y >= 0 && y < 64 && x >= 0 && x < 64) { \
                const float4* s4 = (const float4*)(in + \
                    (((bb * 64 + y) * 64 + x) * 128 + gc * 8)); \
                float4 f0 = s4[0], f1 = s4[1]; \
                ov[0]=f2b(f0.x); ov[1]=f2b(f0.y); ov[2]=f2b(f0.z); ov[3]=f2b(f0.w); \
                ov[4]=f2b(f1.x); ov[5]=f2b(f1.y); ov[6]=f2b(f1.z); ov[7]=f2b(f1.w); \
            } else { \
                _Pragma("unroll") for (int j = 0; j < 8; ++j) ov[j] = 0; \
            } \
            uint4 wv; __builtin_memcpy(&wv, ov, 16); \
            *(uint4*)((char*)ldsA + slot * 16) = wv; \
        } \
    } }

#define LOADB(B, P, S) { \
    _Pragma("unroll") for (int kk = 0; kk < 2; ++kk) \
    _Pragma("unroll") for (int ni = 0; ni < 4; ++ni) \
        B[kk * 4 + ni] = *(const bf16x8*)(BFl + (P) * 32768 + \
                                          ((S) * 2 + kk) * 8192 + ni * 128); }

#define COMPP(B, DH, DW) { \
    _Pragma("unroll") for (int kk = 0; kk < 2; ++kk) { \
        bf16x8 af[4]; \
        _Pragma("unroll") for (int mi = 0; mi < 4; ++mi) { \
            int wp = mi * 16 + l15 + (DW); \
            int swz = (kk * 4 + q) ^ (wp & 7); \
            af[mi] = *(const bf16x8*)((const char*)ldsA + \
                (((DH) * 528 + wp * 8 + swz) << 4)); \
        } \
        _Pragma("unroll") for (int mi = 0; mi < 4; ++mi) \
        _Pragma("unroll") for (int ni = 0; ni < 4; ++ni) \
            acc[mi][ni] = __builtin_amdgcn_mfma_f32_16x16x32_bf16( \
                af[mi], B[kk * 4 + ni], acc[mi][ni], 0, 0, 0); } }

    const u16* BFl = BF + (q * 2048 + (wn0 + l15) * 8);

    f32x4 zero = {0.f, 0.f, 0.f, 0.f};
    f32x4 acc[4][4];
    #pragma unroll
    for (int mi = 0; mi < 4; ++mi)
        #pragma unroll
        for (int ni = 0; ni < 4; ++ni) acc[mi][ni] = zero;

    bf16x8 B0[8], B1[8];

    // ---- channel half 0 ----
    STAGE(0);
    __syncthreads();
    LOADB(B0, 0, 0);
    LOADB(B1, 1, 0); COMPP(B0, 0, 0);
    LOADB(B0, 2, 0); COMPP(B1, 0, 1);
    LOADB(B1, 3, 0); COMPP(B0, 0, 2);
    LOADB(B0, 4, 0); COMPP(B1, 1, 0);
    LOADB(B1, 5, 0); COMPP(B0, 1, 1);
    LOADB(B0, 6, 0); COMPP(B1, 1, 2);
    LOADB(B1, 7, 0); COMPP(B0, 2, 0);
    LOADB(B0, 8, 0); COMPP(B1, 2, 1);
    COMPP(B0, 2, 2);
    __syncthreads();                              // all half-0 LDS reads done

    // ---- channel half 1 ----
    STAGE(1);
    __syncthreads();
    LOADB(B0, 0, 1);
    LOADB(B1, 1, 1); COMPP(B0, 0, 0);
    LOADB(B0, 2, 1); COMPP(B1, 0, 1);
    LOADB(B1, 3, 1); COMPP(B0, 0, 2);
    LOADB(B0, 4, 1); COMPP(B1, 1, 0);
    LOADB(B1, 5, 1); COMPP(B0, 1, 1);
    LOADB(B0, 6, 1); COMPP(B1, 1, 2);
    LOADB(B1, 7, 1); COMPP(B0, 2, 0);
    LOADB(B0, 8, 1); COMPP(B1, 2, 1);
    COMPP(B0, 2, 2);

    // epilogue: bias + relu, store bf16 x, column sums -> s0
    float bv[4];
    #pragma unroll
    for (int ni = 0; ni < 4; ++ni) bv[ni] = bias[wn0 + ni * 16 + l15];
    float colsum[4] = {0.f, 0.f, 0.f, 0.f};
    u16* xrow = X + (((bb << 12) + (h << 6) + q * 4) * 256) + wn0 + l15;
    #pragma unroll
    for (int mi = 0; mi < 4; ++mi) {
        #pragma unroll
        for (int rr = 0; rr < 4; ++rr) {
            u16* xp = xrow + (mi * 16 + rr) * 256;
            #pragma unroll
            for (int ni = 0; ni < 4; ++ni) {
                float v = acc[mi][ni][rr] + bv[ni];
                v = v > 0.f ? v : 0.f;
                xp[ni * 16] = f2b(v);
                colsum[ni] += v;
            }
        }
    }
    #pragma unroll
    for (int ni = 0; ni < 4; ++ni) {
        float c = colsum[ni];
        c += __shfl_xor(c, 16);
        c += __shfl_xor(c, 32);
        if (lane < 16) atomicAdd(&s0[bb * 256 + wn0 + ni * 16 + l15], c);
    }
#undef STAGE
#undef LOADB
#undef COMPP
}

// ---------------------------------------------------------------------------
// routing pass v3 (R9/R11-measured best): 64 positions/block, grid 64x16 =
// 1024 blocks (4 blocks/CU -> enough TLP; 256-pos/1-block-per-CU variant
// regressed 40us in R12). vsum = l2n(Sa) (+ l2n(Sb)) register-cached -> ONE
// dot per position. Stride-17 LDS, 8 outstanding X-loads, shfl n-reduce.
// thread (c=t&15, nl=t>>4). b-logits bounded -> no softmax max pass.
// ---------------------------------------------------------------------------
__launch_bounds__(256, 4)
__global__ void k_pass(const u16* __restrict__ X, const float* __restrict__ Sa,
                       const float* __restrict__ Sb, float* __restrict__ Sout,
                       int use2) {
    __shared__ float vs[272];                     // [cap*17 + d]
    __shared__ float red[4 * 272];                // [wave][c*17 + d]
    const int t = threadIdx.x, b = blockIdx.y, chunk = blockIdx.x;
    const int c = t & 15, nl = t >> 4;
    const int lane = t & 63, wid = t >> 6;
    {
        float sa = Sa[b * 256 + t];
        float ss = sa * sa;
        #pragma unroll
        for (int off = 1; off < 16; off <<= 1) ss += __shfl_xor(ss, off);
        ss = ss < 1e-12f ? 1e-12f : ss;
        float vv = sa / sqrtf(ss);
        if (use2) {
            float sb = Sb[b * 256 + t];
            float s2v = sb * sb;
            #pragma unroll
            for (int off = 1; off < 16; off <<= 1) s2v += __shfl_xor(s2v, off);
            s2v = s2v < 1e-12f ? 1e-12f : s2v;
            vv += sb / sqrtf(s2v);
        }
        vs[(t >> 4) * 17 + (t & 15)] = vv;
    }
    // prefetch all 4 positions (8 outstanding 16B loads) while v finishes
    const u16* xbase = X + ((b << 12) + chunk * 64 + nl) * 256 + c * 16;
    uint4 pa[8];
    #pragma unroll
    for (int r = 0; r < 4; ++r) {
        pa[2 * r]     = ((const uint4*)(xbase + r * 4096))[0];
        pa[2 * r + 1] = ((const uint4*)(xbase + r * 4096))[1];
    }
    __syncthreads();
    // register-cache this thread's vsum row (conflict-free: stride 17)
    float vr[16];
    #pragma unroll
    for (int d = 0; d < 16; ++d) vr[d] = vs[c * 17 + d];

    float acc[16];
    #pragma unroll
    for (int d = 0; d < 16; ++d) acc[d] = 0.f;

    #pragma unroll
    for (int r = 0; r < 4; ++r) {
        u32 us[8];
        __builtin_memcpy(us, &pa[2 * r], 32);
        float xf[16];
        #pragma unroll
        for (int j = 0; j < 8; ++j) { xf[2*j] = blo(us[j]); xf[2*j+1] = bhi(us[j]); }
        float bvv = 0.f;
        #pragma unroll
        for (int d = 0; d < 16; ++d) bvv += xf[d] * vr[d];
        float e = __expf(bvv);                    // |b| small: stable w/o max
        float sm = e;
        #pragma unroll
        for (int off = 1; off < 16; off <<= 1) sm += __shfl_xor(sm, off);
        float w = e / sm;
        #pragma unroll
        for (int d = 0; d < 16; ++d) acc[d] += w * xf[d];
    }
    // reduce the wave's 4 nl groups (lanes +-16, +-32) -> lanes 0..15
    #pragma unroll
    for (int d = 0; d < 16; ++d) {
        acc[d] += __shfl_xor(acc[d], 16);
        acc[d] += __shfl_xor(acc[d], 32);
    }
    if (lane < 16) {
        #pragma unroll
        for (int d = 0; d < 16; ++d) red[wid * 272 + lane * 17 + d] = acc[d];
    }
    __syncthreads();
    {
        int c2 = t >> 4, d2 = t & 15;
        float tot = red[c2 * 17 + d2]       + red[272 + c2 * 17 + d2]
                  + red[544 + c2 * 17 + d2] + red[816 + c2 * 17 + d2];
        atomicAdd(&Sout[b * 256 + t], tot);
    }
}

// ---------------------------------------------------------------------------
// final: v = l2_normalize(s3), broadcast to (B,64,64,256) fp32.
// v hoisted to a register (loop-invariant per thread).
// ---------------------------------------------------------------------------
__launch_bounds__(256, 4)
__global__ void k_bcast(const float* __restrict__ S, float* __restrict__ Out) {
    __shared__ float vls[256];
    int t = threadIdx.x, bx = blockIdx.x, b = blockIdx.y;
    float s = S[b * 256 + t];
    float ss = s * s;
    #pragma unroll
    for (int off = 1; off < 16; off <<= 1) ss += __shfl_xor(ss, off);
    ss = ss < 1e-12f ? 1e-12f : ss;
    vls[t] = s / sqrtf(ss);
    __syncthreads();
    float4 myv = ((const float4*)vls)[t & 63];    // (j*256+t)&63 == t&63
    float4* o = (float4*)Out + (long)b * 262144 + bx * 4096;
    #pragma unroll
    for (int j = 0; j < 16; ++j) o[j * 256 + t] = myv;
}

// ---------------------------------------------------------------------------
extern "C" void kernel_launch(void* const* d_in, const int* in_sizes, int n_in,
                              void* d_out, int out_size, void* d_ws, size_t ws_size,
                              hipStream_t stream) {
    const float* in   = (const float*)d_in[0];   // (16,64,64,128)
    const float* wk   = (const float*)d_in[1];   // (3,3,128,256)
    const float* bias = (const float*)d_in[2];   // (256,)
    float* out = (float*)d_out;
    char* ws = (char*)d_ws;

    // workspace layout (bytes) — pad tensor eliminated
    const size_t OFF_BF  = 0;                    // 294912*2      =    589,824
    const size_t OFF_X   = 589824;               // 16*4096*256*2 = 33,554,432
    const size_t OFF_ST  = 34144256;             // s0,s2,s3      = 3*16,384
    const size_t NEEDED  = OFF_ST + 3 * 16384;
    if (ws_size < NEEDED) return;                // fail loudly (validation error)

    u16* BF  = (u16*)(ws + OFF_BF);
    u16* X   = (u16*)(ws + OFF_X);
    float* s0 = (float*)(ws + OFF_ST);
    float* s2 = s0 + 4096;
    float* s3 = s2 + 4096;

    k_prep <<<1200, 256, 0, stream>>>(wk, BF, s0);
    k_conv <<<1024, 256, 0, stream>>>(in, BF, bias, X, s0);
    k_pass <<<dim3(64, 16), 256, 0, stream>>>(X, s0, s0, s2, 0);
    k_pass <<<dim3(64, 16), 256, 0, stream>>>(X, s0, s2, s3, 1);
    k_bcast<<<dim3(64, 16), 256, 0, stream>>>(s3, out);
}